// Round 1
// baseline (2148.593 us; speedup 1.0000x reference)
//
#include <hip/hip_runtime.h>

// ISTFT: B=8, T=2048 frames, NFFT=1024, HOP=256, FREQ=513.
// out_len = (T-1)*HOP + NFFT = 525056; cropped by NFFT/2=512 each side -> 524032 cols.
//
// Folded projection (Hermitian symmetry of the given W matrices):
//   frames[b,t,n] = sum_{k=0}^{512} f_k * ( W_real[k][n]*fr[b,t,k] - W_imag[k][n]*fi[b,t,k] )
//   with f_k = 2 for 1<=k<=511, else 1.
// OLA gather: out sample s = 256*t + n; for segment g (s = 256g + ls, ls in [0,256)),
//   contributions are exactly (t = g-j, n = ls + 256j), j = 0..3, for valid t.

#define NFFT    1024
#define HOP     256
#define FREQ    513
#define BATCH   8
#define NFRAMES 2048
#define OUTCOLS 524032
#define CROP    512

__global__ __launch_bounds__(256) void istft_fused_kernel(
    const float* __restrict__ re,   // (B,1,T,FREQ)
    const float* __restrict__ im,   // (B,1,T,FREQ)
    const float* __restrict__ Wr,   // (NFFT k, NFFT n)
    const float* __restrict__ Wi,   // (NFFT k, NFFT n)
    const float* __restrict__ ola,  // (NFFT)
    float* __restrict__ out)        // (B, OUTCOLS)
{
    const int g  = blockIdx.x + 2;   // segment index: 2..2048
    const int b  = blockIdx.y;
    const int ls = threadIdx.x;      // 0..255

    __shared__ float s_fr[4][FREQ];
    __shared__ float s_fi[4][FREQ];

    // Stage the (up to) 4 needed spectra, pre-scaled by the Hermitian fold factor.
    #pragma unroll
    for (int j = 0; j < 4; ++j) {
        const int t = g - j;
        const bool valid = (t >= 0 && t < NFRAMES);
        const int tc = valid ? t : 0;
        const size_t base = ((size_t)b * NFRAMES + tc) * FREQ;
        for (int k = ls; k < FREQ; k += 256) {
            const float f = (k == 0 || k == FREQ - 1) ? 1.0f : 2.0f;
            s_fr[j][k] = valid ? re[base + k] * f : 0.0f;
            s_fi[j][k] = valid ? im[base + k] * f : 0.0f;
        }
    }
    __syncthreads();

    // Each thread owns output sample s = 256*g + ls; its 4 contributions use
    // W columns n_j = ls + 256*j (coalesced across lanes).
    const float* __restrict__ wr = Wr + ls;
    const float* __restrict__ wi = Wi + ls;

    float acc = 0.0f;
    for (int k = 0; k < FREQ; ++k) {
        const float* __restrict__ wrk = wr + (size_t)k * NFFT;
        const float* __restrict__ wik = wi + (size_t)k * NFFT;
        #pragma unroll
        for (int j = 0; j < 4; ++j) {
            acc = fmaf( wrk[j * HOP], s_fr[j][k], acc);
            acc = fmaf(-wik[j * HOP], s_fi[j][k], acc);
        }
    }

    // Window-sum normalization (same validity mask as the reference scatter).
    float ws = 0.0f;
    #pragma unroll
    for (int j = 0; j < 4; ++j) {
        const int t = g - j;
        if (t >= 0 && t < NFRAMES) ws += ola[ls + j * HOP];
    }
    ws = fmaxf(ws, 1e-11f);

    const int s = g * HOP + ls;
    out[(size_t)b * OUTCOLS + (s - CROP)] = acc / ws;
}

extern "C" void kernel_launch(void* const* d_in, const int* in_sizes, int n_in,
                              void* d_out, int out_size, void* d_ws, size_t ws_size,
                              hipStream_t stream) {
    const float* re  = (const float*)d_in[0];
    const float* im  = (const float*)d_in[1];
    const float* Wr  = (const float*)d_in[2];
    const float* Wi  = (const float*)d_in[3];
    const float* ola = (const float*)d_in[4];
    float* out = (float*)d_out;

    dim3 grid(2047, BATCH);  // g = 2..2048 covers cropped samples exactly
    dim3 block(256);
    hipLaunchKernelGGL(istft_fused_kernel, grid, block, 0, stream,
                       re, im, Wr, Wi, ola, out);
}

// Round 2
// 148.213 us; speedup vs baseline: 14.4967x; 14.4967x over previous
//
#include <hip/hip_runtime.h>

// Fused ISTFT as a single MFMA GEMM:
//   out[(b,g)][ls] = ( sum_{k''} A[(b,g)][k''] * Bfold[k''][ls] ) / wsum
// with k'' = 4*kk + j (kk in [0,1056) padded per-j index, j in [0,4)),
//   A[(b,g)][k''] = spec[b][t=g-j][kk]   (re for kk<513, im for 513<=kk<1026, 0 pad)
//   Bfold[k''][ls] = f(kk)*Wr[kk][ls+256j]  or  -f(kk-513)*Wi[kk-513][ls+256j]
//   f = 2 except at DC/Nyquist (Hermitian fold), baked into B at prep time.
// out flat index = m*256 + ls where m = b*2047 + (g-2).

#define BATCH    8
#define NFRAMES  2048
#define FREQ     513
#define NFFT     1024
#define HOP      256
#define OUTCOLS  524032      // 2047*256
#define MROWS    16376       // 8*2047
#define GI_PER_B 2047
#define BK       64
#define NKT      66          // K'' = 4224 = 66*64
#define BM       64
#define BSBYTES  (NKT * 32768)  // 2,162,688 B of pre-swizzled bf16 B

typedef __attribute__((ext_vector_type(8))) short bf16x8;
typedef __attribute__((ext_vector_type(4))) float f32x4;

__device__ __forceinline__ unsigned short f2bf(float x) {
    unsigned u = __float_as_uint(x);
    return (unsigned short)((u + 0x7fffu + ((u >> 16) & 1u)) >> 16);
}

// ---------------- prep kernel: build pre-swizzled bf16 B into ws ----------------
// Bs is stored as 66 K-tiles of 32KB, each a [256 n][64 k] bf16 image laid out so
// that a LINEAR global_load_lds copy + XOR-swizzled ds_read returns B[n][k]:
//   storage byte of (n,k) = (n*128 + k*2) ^ ((n&7)<<4)
__global__ __launch_bounds__(256) void prep_B(const float* __restrict__ Wr,
                                              const float* __restrict__ Wi,
                                              unsigned short* __restrict__ Bs) {
    int id  = blockIdx.x * 256 + threadIdx.x;   // 66*8192 dwords total
    int kt  = id >> 13;
    int rem = id & 8191;
    int n   = rem >> 5;        // 0..255
    int k0  = (rem & 31) * 2;  // even k
    unsigned short h[2];
#pragma unroll
    for (int i = 0; i < 2; ++i) {
        int k  = k0 + i;
        int kg = kt * 64 + k;      // k'' global
        int kk = kg >> 2;          // padded per-j index
        int j  = kg & 3;
        float v = 0.0f;
        if (kk < FREQ) {
            float f = (kk == 0 || kk == FREQ - 1) ? 1.0f : 2.0f;
            v = f * Wr[(size_t)kk * NFFT + n + 256 * j];
        } else if (kk < 2 * FREQ) {
            int k2 = kk - FREQ;
            float f = (k2 == 0 || k2 == FREQ - 1) ? 1.0f : 2.0f;
            v = -f * Wi[(size_t)k2 * NFFT + n + 256 * j];
        }
        h[i] = f2bf(v);
    }
    unsigned d = (unsigned)h[0] | ((unsigned)h[1] << 16);
    unsigned byteoff = (unsigned)((n << 7) + (k0 << 1)) ^ (unsigned)((n & 7) << 4);
    *(unsigned*)((char*)Bs + (size_t)kt * 32768 + byteoff) = d;
}

// ---------------- main fused GEMM kernel ----------------
__global__ __launch_bounds__(256) void istft_mfma(
    const float* __restrict__ re, const float* __restrict__ im,
    const float* __restrict__ ola,
    const unsigned short* __restrict__ Bs,
    float* __restrict__ out) {
    __shared__ __attribute__((aligned(16))) unsigned short Abuf[2][BM][72]; // +8 pad: 2-way = free
    __shared__ __attribute__((aligned(16))) unsigned short Bbuf[2][16384];  // linear, swizzle on read
    __shared__ float s_wsum[256], s_ola0[256], s_ola3[256];

    const int tid = threadIdx.x;
    const int l   = tid & 63;
    const int w   = tid >> 6;
    const int mt  = blockIdx.x;

    {   // wsum tables (interior wsum + edge-correction terms)
        float o0 = ola[tid], o1 = ola[tid + 256], o2 = ola[tid + 512], o3 = ola[tid + 768];
        s_wsum[tid] = o0 + o1 + o2 + o3;
        s_ola0[tid] = o0;
        s_ola3[tid] = o3;
    }

    // ---- per-thread A staging geometry: row r, 16-elem segment q ----
    const int r = tid >> 2;      // 0..63
    const int q = tid & 3;       // 0..3
    const int m = mt * BM + r;
    int b = 0, gi = 0;
    const bool mrow_ok = (m < MROWS);
    if (mrow_ok) { b = m / GI_PER_B; gi = m - b * GI_PER_B; }
    const int g = gi + 2;
    int baseT[4];
#pragma unroll
    for (int j = 0; j < 4; ++j) {
        int t = g - j;
        baseT[j] = (mrow_ok && t >= 0 && t < NFRAMES) ? (b * NFRAMES + t) * FREQ : -1;
    }

    float areg[16];

    auto A_LOAD = [&](int kt) {
        int kkbase = kt * 16 + q * 4;
#pragma unroll
        for (int d = 0; d < 4; ++d) {
            int kk = kkbase + d;
#pragma unroll
            for (int j = 0; j < 4; ++j) {
                float v = 0.0f;
                if (baseT[j] >= 0) {
                    if (kk < FREQ)          v = re[baseT[j] + kk];
                    else if (kk < 2 * FREQ) v = im[baseT[j] + kk - FREQ];
                }
                areg[d * 4 + j] = v;   // k'' = 4*kk + j ordering
            }
        }
    };
    auto A_WRITE = [&](int buf) {
        bf16x8 v0, v1;
#pragma unroll
        for (int i = 0; i < 8; ++i) v0[i] = (short)f2bf(areg[i]);
#pragma unroll
        for (int i = 0; i < 8; ++i) v1[i] = (short)f2bf(areg[8 + i]);
        *(bf16x8*)&Abuf[buf][r][q * 16]     = v0;
        *(bf16x8*)&Abuf[buf][r][q * 16 + 8] = v1;
    };
    auto B_STAGE = [&](int kt, int buf) {
        const char* src = (const char*)Bs + (size_t)kt * 32768 + (size_t)w * 8192 + (size_t)l * 16;
        char* dst = (char*)&Bbuf[buf][0] + w * 8192;   // wave-uniform base; HW adds lane*16
#pragma unroll
        for (int c = 0; c < 8; ++c) {
            __builtin_amdgcn_global_load_lds(
                (const __attribute__((address_space(1))) unsigned int*)(src + c * 1024),
                (__attribute__((address_space(3))) unsigned int*)(dst + c * 1024),
                16, 0, 0);
        }
    };

    f32x4 acc[4][4];
#pragma unroll
    for (int i = 0; i < 4; ++i)
#pragma unroll
        for (int j = 0; j < 4; ++j) acc[i][j] = (f32x4){0.f, 0.f, 0.f, 0.f};

    auto COMPUTE = [&](int buf) {
#pragma unroll
        for (int ks = 0; ks < 2; ++ks) {
            const int krow = ks * 32 + (l >> 4) * 8;
            bf16x8 af[4], bfr[4];
#pragma unroll
            for (int mb = 0; mb < 4; ++mb)
                af[mb] = *(const bf16x8*)&Abuf[buf][mb * 16 + (l & 15)][krow];
#pragma unroll
            for (int nb = 0; nb < 4; ++nb) {
                const int nn = w * 64 + nb * 16 + (l & 15);
                unsigned off = (unsigned)((nn << 7) + (krow << 1)) ^ (unsigned)((nn & 7) << 4);
                bfr[nb] = *(const bf16x8*)((const char*)&Bbuf[buf][0] + off);
            }
#pragma unroll
            for (int mb = 0; mb < 4; ++mb)
#pragma unroll
                for (int nb = 0; nb < 4; ++nb)
                    acc[mb][nb] = __builtin_amdgcn_mfma_f32_16x16x32_bf16(af[mb], bfr[nb], acc[mb][nb], 0, 0, 0);
        }
    };

    // ---- 2-phase double-buffered pipeline ----
    A_LOAD(0);
    B_STAGE(0, 0);
    A_WRITE(0);
    __syncthreads();

    for (int kt = 0; kt < NKT; ++kt) {
        const int cur = kt & 1, nxt = cur ^ 1;
        if (kt + 1 < NKT) { A_LOAD(kt + 1); B_STAGE(kt + 1, nxt); }
        COMPUTE(cur);
        if (kt + 1 < NKT) A_WRITE(nxt);
        __syncthreads();
    }

    // ---- epilogue: /wsum with edge corrections, direct store ----
    const int row_base = (l >> 4) * 4;
#pragma unroll
    for (int mb = 0; mb < 4; ++mb) {
#pragma unroll
        for (int rr = 0; rr < 4; ++rr) {
            int ml = mb * 16 + row_base + rr;
            int mg = mt * BM + ml;
            if (mg >= MROWS) continue;
            int bb = mg / GI_PER_B;
            int gg = mg - bb * GI_PER_B;   // gi = g-2
#pragma unroll
            for (int nb = 0; nb < 4; ++nb) {
                int n = w * 64 + nb * 16 + (l & 15);
                float ws = s_wsum[n];
                if (gg == 0) ws -= s_ola3[n];              // g=2: j=3 invalid
                if (gg == GI_PER_B - 1) ws -= s_ola0[n];   // g=2048: j=0 invalid
                ws = fmaxf(ws, 1e-11f);
                out[(size_t)mg * 256 + n] = acc[mb][nb][rr] / ws;
            }
        }
    }
}

// ---------------- fallback (round-1 kernel) if ws too small ----------------
__global__ __launch_bounds__(256) void istft_fused_kernel(
    const float* __restrict__ re, const float* __restrict__ im,
    const float* __restrict__ Wr, const float* __restrict__ Wi,
    const float* __restrict__ ola, float* __restrict__ out) {
    const int g = blockIdx.x + 2;
    const int b = blockIdx.y;
    const int ls = threadIdx.x;
    __shared__ float s_fr[4][FREQ];
    __shared__ float s_fi[4][FREQ];
#pragma unroll
    for (int j = 0; j < 4; ++j) {
        const int t = g - j;
        const bool valid = (t >= 0 && t < NFRAMES);
        const int tc = valid ? t : 0;
        const size_t base = ((size_t)b * NFRAMES + tc) * FREQ;
        for (int k = ls; k < FREQ; k += 256) {
            const float f = (k == 0 || k == FREQ - 1) ? 1.0f : 2.0f;
            s_fr[j][k] = valid ? re[base + k] * f : 0.0f;
            s_fi[j][k] = valid ? im[base + k] * f : 0.0f;
        }
    }
    __syncthreads();
    const float* wr = Wr + ls;
    const float* wi = Wi + ls;
    float acc = 0.0f;
    for (int k = 0; k < FREQ; ++k) {
        const float* wrk = wr + (size_t)k * NFFT;
        const float* wik = wi + (size_t)k * NFFT;
#pragma unroll
        for (int j = 0; j < 4; ++j) {
            acc = fmaf(wrk[j * HOP], s_fr[j][k], acc);
            acc = fmaf(-wik[j * HOP], s_fi[j][k], acc);
        }
    }
    float ws = 0.0f;
#pragma unroll
    for (int j = 0; j < 4; ++j) {
        const int t = g - j;
        if (t >= 0 && t < NFRAMES) ws += ola[ls + j * HOP];
    }
    ws = fmaxf(ws, 1e-11f);
    const int s = g * HOP + ls;
    out[(size_t)b * OUTCOLS + (s - 512)] = acc / ws;
}

extern "C" void kernel_launch(void* const* d_in, const int* in_sizes, int n_in,
                              void* d_out, int out_size, void* d_ws, size_t ws_size,
                              hipStream_t stream) {
    const float* re  = (const float*)d_in[0];
    const float* im  = (const float*)d_in[1];
    const float* Wr  = (const float*)d_in[2];
    const float* Wi  = (const float*)d_in[3];
    const float* ola = (const float*)d_in[4];
    float* out = (float*)d_out;

    if (ws_size < (size_t)BSBYTES) {
        dim3 grid(2047, BATCH);
        hipLaunchKernelGGL(istft_fused_kernel, grid, dim3(256), 0, stream,
                           re, im, Wr, Wi, ola, out);
        return;
    }
    unsigned short* Bs = (unsigned short*)d_ws;
    hipLaunchKernelGGL(prep_B, dim3(2112), dim3(256), 0, stream, Wr, Wi, Bs);
    hipLaunchKernelGGL(istft_mfma, dim3(256), dim3(256), 0, stream, re, im, ola, Bs, out);
}

// Round 3
// 116.509 us; speedup vs baseline: 18.4414x; 1.2721x over previous
//
#include <hip/hip_runtime.h>

// Fused ISTFT as a single MFMA GEMM:
//   out[(b,g)][ls] = ( sum_{k''} A[(b,g)][k''] * Bfold[k''][ls] ) / wsum
// with k'' = 4*kk + j (kk in [0,1056) padded per-j index, j in [0,4)),
//   A[(b,g)][k''] = spec[b][t=g-j][kk]   (re for kk<513, im for 513<=kk<1026, 0 pad)
//   Bfold[k''][ls] = f(kk)*Wr[kk][ls+256j]  or  -f(kk-513)*Wi[kk-513][ls+256j]
// out flat index = m*256 + ls where m = b*2047 + (g-2).
//
// Round 3: 512-thread blocks (8 waves = 2/SIMD, was 1/SIMD) to hide the
// per-K-tile barrier-drain latency; per-thread staging work halved.

#define BATCH    8
#define NFRAMES  2048
#define FREQ     513
#define NFFT     1024
#define HOP      256
#define OUTCOLS  524032      // 2047*256
#define MROWS    16376       // 8*2047
#define GI_PER_B 2047
#define BK       64
#define NKT      66          // K'' = 4224 = 66*64
#define BM       64
#define BSBYTES  (NKT * 32768)  // 2,162,688 B of pre-swizzled bf16 B

typedef __attribute__((ext_vector_type(8))) short bf16x8;
typedef __attribute__((ext_vector_type(4))) float f32x4;

__device__ __forceinline__ unsigned short f2bf(float x) {
    unsigned u = __float_as_uint(x);
    return (unsigned short)((u + 0x7fffu + ((u >> 16) & 1u)) >> 16);
}

// ---------------- prep kernel: build pre-swizzled bf16 B into ws ----------------
// Bs: 66 K-tiles of 32KB, each a [256 n][64 k] bf16 image laid out so that a
// LINEAR global_load_lds copy + XOR-swizzled ds_read returns B[n][k]:
//   storage byte of (n,k) = (n*128 + k*2) ^ ((n&7)<<4)
__global__ __launch_bounds__(256) void prep_B(const float* __restrict__ Wr,
                                              const float* __restrict__ Wi,
                                              unsigned short* __restrict__ Bs) {
    int id  = blockIdx.x * 256 + threadIdx.x;   // 66*8192 dwords total
    int kt  = id >> 13;
    int rem = id & 8191;
    int n   = rem >> 5;        // 0..255
    int k0  = (rem & 31) * 2;  // even k
    unsigned short h[2];
#pragma unroll
    for (int i = 0; i < 2; ++i) {
        int k  = k0 + i;
        int kg = kt * 64 + k;      // k'' global
        int kk = kg >> 2;          // padded per-j index
        int j  = kg & 3;
        float v = 0.0f;
        if (kk < FREQ) {
            float f = (kk == 0 || kk == FREQ - 1) ? 1.0f : 2.0f;
            v = f * Wr[(size_t)kk * NFFT + n + 256 * j];
        } else if (kk < 2 * FREQ) {
            int k2 = kk - FREQ;
            float f = (k2 == 0 || k2 == FREQ - 1) ? 1.0f : 2.0f;
            v = -f * Wi[(size_t)k2 * NFFT + n + 256 * j];
        }
        h[i] = f2bf(v);
    }
    unsigned d = (unsigned)h[0] | ((unsigned)h[1] << 16);
    unsigned byteoff = (unsigned)((n << 7) + (k0 << 1)) ^ (unsigned)((n & 7) << 4);
    *(unsigned*)((char*)Bs + (size_t)kt * 32768 + byteoff) = d;
}

// ---------------- main fused GEMM kernel (512 threads, 8 waves) ----------------
__global__ __launch_bounds__(512, 2) void istft_mfma(
    const float* __restrict__ re, const float* __restrict__ im,
    const float* __restrict__ ola,
    const unsigned short* __restrict__ Bs,
    float* __restrict__ out) {
    __shared__ __attribute__((aligned(16))) unsigned short Abuf[2][BM][72]; // +8 pad
    __shared__ __attribute__((aligned(16))) unsigned short Bbuf[2][16384];  // linear, swizzle on read
    __shared__ float s_wsum[256], s_ola0[256], s_ola3[256];

    const int tid = threadIdx.x;
    const int l   = tid & 63;
    const int w   = tid >> 6;     // 0..7
    const int wm  = w >> 2;       // 0..1  (M half)
    const int wn  = w & 3;        // 0..3  (N quarter)
    const int mt  = blockIdx.x;

    if (tid < 256) {   // wsum tables (interior wsum + edge-correction terms)
        float o0 = ola[tid], o1 = ola[tid + 256], o2 = ola[tid + 512], o3 = ola[tid + 768];
        s_wsum[tid] = o0 + o1 + o2 + o3;
        s_ola0[tid] = o0;
        s_ola3[tid] = o3;
    }

    // ---- per-thread A staging geometry: row r (8 threads/row), oct o ----
    const int r = tid >> 3;      // 0..63
    const int o = tid & 7;       // 0..7, owns k''-local o*8..o*8+7
    const int m = mt * BM + r;
    int b = 0, gi = 0;
    const bool mrow_ok = (m < MROWS);
    if (mrow_ok) { b = m / GI_PER_B; gi = m - b * GI_PER_B; }
    const int g = gi + 2;
    int baseT[4];
#pragma unroll
    for (int j = 0; j < 4; ++j) {
        int t = g - j;
        baseT[j] = (mrow_ok && t >= 0 && t < NFRAMES) ? (b * NFRAMES + t) * FREQ : -1;
    }

    float areg[8];

    auto A_LOAD = [&](int kt) {
        int kkbase = kt * 16 + o * 2;
#pragma unroll
        for (int d = 0; d < 2; ++d) {
            int kk = kkbase + d;
#pragma unroll
            for (int j = 0; j < 4; ++j) {
                float v = 0.0f;
                if (baseT[j] >= 0) {
                    if (kk < FREQ)          v = re[baseT[j] + kk];
                    else if (kk < 2 * FREQ) v = im[baseT[j] + kk - FREQ];
                }
                areg[d * 4 + j] = v;   // k''-local = o*8 + d*4 + j
            }
        }
    };
    auto A_WRITE = [&](int buf) {
        bf16x8 v;
#pragma unroll
        for (int i = 0; i < 8; ++i) v[i] = (short)f2bf(areg[i]);
        *(bf16x8*)&Abuf[buf][r][o * 8] = v;
    };
    auto B_STAGE = [&](int kt, int buf) {
        const char* src = (const char*)Bs + (size_t)kt * 32768 + (size_t)w * 4096 + (size_t)l * 16;
        char* dst = (char*)&Bbuf[buf][0] + w * 4096;   // wave-uniform base; HW adds lane*16
#pragma unroll
        for (int c = 0; c < 4; ++c) {
            __builtin_amdgcn_global_load_lds(
                (const __attribute__((address_space(1))) unsigned int*)(src + c * 1024),
                (__attribute__((address_space(3))) unsigned int*)(dst + c * 1024),
                16, 0, 0);
        }
    };

    f32x4 acc[2][4];
#pragma unroll
    for (int i = 0; i < 2; ++i)
#pragma unroll
        for (int j = 0; j < 4; ++j) acc[i][j] = (f32x4){0.f, 0.f, 0.f, 0.f};

    auto COMPUTE = [&](int buf) {
#pragma unroll
        for (int ks = 0; ks < 2; ++ks) {
            const int krow = ks * 32 + (l >> 4) * 8;
            bf16x8 af[2], bfr[4];
#pragma unroll
            for (int mb = 0; mb < 2; ++mb)
                af[mb] = *(const bf16x8*)&Abuf[buf][wm * 32 + mb * 16 + (l & 15)][krow];
#pragma unroll
            for (int nb = 0; nb < 4; ++nb) {
                const int nn = wn * 64 + nb * 16 + (l & 15);
                unsigned off = (unsigned)((nn << 7) + (krow << 1)) ^ (unsigned)((nn & 7) << 4);
                bfr[nb] = *(const bf16x8*)((const char*)&Bbuf[buf][0] + off);
            }
#pragma unroll
            for (int mb = 0; mb < 2; ++mb)
#pragma unroll
                for (int nb = 0; nb < 4; ++nb)
                    acc[mb][nb] = __builtin_amdgcn_mfma_f32_16x16x32_bf16(af[mb], bfr[nb], acc[mb][nb], 0, 0, 0);
        }
    };

    // ---- 2-phase double-buffered pipeline ----
    A_LOAD(0);
    B_STAGE(0, 0);
    A_WRITE(0);
    __syncthreads();

    for (int kt = 0; kt < NKT; ++kt) {
        const int cur = kt & 1, nxt = cur ^ 1;
        if (kt + 1 < NKT) { A_LOAD(kt + 1); B_STAGE(kt + 1, nxt); }
        COMPUTE(cur);
        if (kt + 1 < NKT) A_WRITE(nxt);
        __syncthreads();
    }

    // ---- epilogue: /wsum with edge corrections, direct store ----
    const int row_base = (l >> 4) * 4;
#pragma unroll
    for (int mb = 0; mb < 2; ++mb) {
#pragma unroll
        for (int rr = 0; rr < 4; ++rr) {
            int ml = wm * 32 + mb * 16 + row_base + rr;
            int mg = mt * BM + ml;
            if (mg >= MROWS) continue;
            int bb = mg / GI_PER_B;
            int gg = mg - bb * GI_PER_B;   // gi = g-2
#pragma unroll
            for (int nb = 0; nb < 4; ++nb) {
                int n = wn * 64 + nb * 16 + (l & 15);
                float ws = s_wsum[n];
                if (gg == 0) ws -= s_ola3[n];              // g=2: j=3 invalid
                if (gg == GI_PER_B - 1) ws -= s_ola0[n];   // g=2048: j=0 invalid
                ws = fmaxf(ws, 1e-11f);
                out[(size_t)mg * 256 + n] = acc[mb][nb][rr] / ws;
            }
        }
    }
}

// ---------------- fallback (round-1 kernel) if ws too small ----------------
__global__ __launch_bounds__(256) void istft_fused_kernel(
    const float* __restrict__ re, const float* __restrict__ im,
    const float* __restrict__ Wr, const float* __restrict__ Wi,
    const float* __restrict__ ola, float* __restrict__ out) {
    const int g = blockIdx.x + 2;
    const int b = blockIdx.y;
    const int ls = threadIdx.x;
    __shared__ float s_fr[4][FREQ];
    __shared__ float s_fi[4][FREQ];
#pragma unroll
    for (int j = 0; j < 4; ++j) {
        const int t = g - j;
        const bool valid = (t >= 0 && t < NFRAMES);
        const int tc = valid ? t : 0;
        const size_t base = ((size_t)b * NFRAMES + tc) * FREQ;
        for (int k = ls; k < FREQ; k += 256) {
            const float f = (k == 0 || k == FREQ - 1) ? 1.0f : 2.0f;
            s_fr[j][k] = valid ? re[base + k] * f : 0.0f;
            s_fi[j][k] = valid ? im[base + k] * f : 0.0f;
        }
    }
    __syncthreads();
    const float* wr = Wr + ls;
    const float* wi = Wi + ls;
    float acc = 0.0f;
    for (int k = 0; k < FREQ; ++k) {
        const float* wrk = wr + (size_t)k * NFFT;
        const float* wik = wi + (size_t)k * NFFT;
#pragma unroll
        for (int j = 0; j < 4; ++j) {
            acc = fmaf(wrk[j * HOP], s_fr[j][k], acc);
            acc = fmaf(-wik[j * HOP], s_fi[j][k], acc);
        }
    }
    float ws = 0.0f;
#pragma unroll
    for (int j = 0; j < 4; ++j) {
        const int t = g - j;
        if (t >= 0 && t < NFRAMES) ws += ola[ls + j * HOP];
    }
    ws = fmaxf(ws, 1e-11f);
    const int s = g * HOP + ls;
    out[(size_t)b * OUTCOLS + (s - 512)] = acc / ws;
}

extern "C" void kernel_launch(void* const* d_in, const int* in_sizes, int n_in,
                              void* d_out, int out_size, void* d_ws, size_t ws_size,
                              hipStream_t stream) {
    const float* re  = (const float*)d_in[0];
    const float* im  = (const float*)d_in[1];
    const float* Wr  = (const float*)d_in[2];
    const float* Wi  = (const float*)d_in[3];
    const float* ola = (const float*)d_in[4];
    float* out = (float*)d_out;

    if (ws_size < (size_t)BSBYTES) {
        dim3 grid(2047, BATCH);
        hipLaunchKernelGGL(istft_fused_kernel, grid, dim3(256), 0, stream,
                           re, im, Wr, Wi, ola, out);
        return;
    }
    unsigned short* Bs = (unsigned short*)d_ws;
    hipLaunchKernelGGL(prep_B, dim3(2112), dim3(256), 0, stream, Wr, Wi, Bs);
    hipLaunchKernelGGL(istft_mfma, dim3(256), dim3(512), 0, stream, re, im, ola, Bs, out);
}

// Round 4
// 109.263 us; speedup vs baseline: 19.6643x; 1.0663x over previous
//
#include <hip/hip_runtime.h>

// Fused ISTFT as one MFMA GEMM, j-major K layout:
//   out[(b,g)][n] = ( sum_{k''} A[m'][k''] * Bfold[k''][n] ) / wsum[n]
// k'' = j*1088 + c, c<544: re[kk=c] (kk<513), else im[kk=c-544] (kk<513); zero-pad.
// A[m'][j*1088+c] = spec[b][t = gi+2-j][c-part], m' = b*2048 + gi (gi<=2046 real).
// Bfold[j*1088+c][n] = f(kk)*Wr[kk][n+256j]  /  -f(kk)*Wi[kk][n+256j], f=2 except DC/Nyq.
// out flat = (b*2047+gi)*256 + n.

#define BATCH    8
#define NFRAMES  2048
#define FREQ     513
#define NFFT     1024
#define OUTCOLS  524032
#define NKT      68            // K'' = 4352 = 68*64
#define APITCH   2176          // bytes per frame row (1088 bf16)
#define BSB      (NKT * 32768) // 2,228,224 B  (68 tiles x 2 halves x 16KB)
#define GUARDB   (64 * APITCH) // 139,264
#define AIMG_OFF ((size_t)BSB + GUARDB)
#define WS_NEED  (AIMG_OFF + (size_t)16384 * APITCH + GUARDB)  // 38,158,336

// v3 fallback constants
#define BSBYTES_V3 (66 * 32768)

typedef __attribute__((ext_vector_type(8))) short bf16x8;
typedef __attribute__((ext_vector_type(4))) float f32x4;

__device__ __forceinline__ unsigned short f2bf(float x) {
    unsigned u = __float_as_uint(x);
    return (unsigned short)((u + 0x7fffu + ((u >> 16) & 1u)) >> 16);
}

// ============ prep_A: repack spectra -> padded, row-phase-swizzled bf16 image ============
// Row fm' = b*2048+t = row (re base = row*513). 136 groups of 8 elems per row.
// Group g8<68: re part (c = g8*8+e, valid c<513); g8>=68: im part (ci = c-544).
// Stored group position = (g8&7)^(row&7) within each 64-elem block (16B granularity).
__global__ __launch_bounds__(256) void prep_A(const float* __restrict__ re,
                                              const float* __restrict__ im,
                                              char* __restrict__ ws) {
    const int row = blockIdx.x;          // 0..16383
    const int g8  = threadIdx.x;
    if (g8 >= 136) return;
    const float* src = (g8 < 68) ? (re + (size_t)row * FREQ) : (im + (size_t)row * FREQ);
    const int cbase = (g8 < 68) ? g8 * 8 : g8 * 8 - 544;
    bf16x8 v;
#pragma unroll
    for (int e = 0; e < 8; ++e) {
        int c = cbase + e;
        float x = (c < FREQ) ? src[c] : 0.0f;
        v[e] = (short)f2bf(x);
    }
    char* dst = ws + AIMG_OFF + (size_t)row * APITCH
              + (g8 >> 3) * 128 + (((g8 & 7) ^ (row & 7)) << 4);
    *(bf16x8*)dst = v;
}

// ============ prep_B (v4): 68 tiles x 2 halves x [128 nn][64 k], XOR-swizzled ============
__global__ __launch_bounds__(256) void prep_B4(const float* __restrict__ Wr,
                                               const float* __restrict__ Wi,
                                               char* __restrict__ ws) {
    int id = blockIdx.x * 256 + threadIdx.x;      // dword id, total 557056
    int hid  = id >> 12;        // kt*2+nh  (0..135)
    int rem  = id & 4095;
    int nn   = rem >> 5;        // 0..127
    int dstd = rem & 31;        // stored dword-in-row
    int dsrc = dstd ^ ((nn & 7) << 2);
    int kt = hid >> 1, nh = hid & 1;
    int kg = kt * 64 + dsrc * 2;
    int j  = kg / 1088;
    int c  = kg - j * 1088;
    int col = nh * 128 + nn + 256 * j;
    unsigned short h[2];
#pragma unroll
    for (int e = 0; e < 2; ++e) {
        int ce = c + e;
        float v = 0.0f;
        if (ce < 544) {
            if (ce < FREQ) {
                float f = (ce == 0 || ce == FREQ - 1) ? 1.0f : 2.0f;
                v = f * Wr[(size_t)ce * NFFT + col];
            }
        } else {
            int ci = ce - 544;
            if (ci < FREQ) {
                float f = (ci == 0 || ci == FREQ - 1) ? 1.0f : 2.0f;
                v = -f * Wi[(size_t)ci * NFFT + col];
            }
        }
        h[e] = f2bf(v);
    }
    unsigned d = (unsigned)h[0] | ((unsigned)h[1] << 16);
    *(unsigned*)(ws + (size_t)hid * 16384 + nn * 128 + dstd * 4) = d;
}

// ============ main kernel: BM=128 x BN=128, depth-3 counted-vmcnt pipeline ============
__global__ __launch_bounds__(512, 2) void istft_mfma4(
    const char* __restrict__ ws_c, const float* __restrict__ ola,
    float* __restrict__ out) {
    __shared__ __attribute__((aligned(16))) unsigned short Abuf[3][128][64]; // 48KB
    __shared__ __attribute__((aligned(16))) unsigned short Bbuf[3][128][64]; // 48KB
    __shared__ float s_wsum[256], s_ola0[256], s_ola3[256];

    const int tid = threadIdx.x;
    const int l   = tid & 63;
    const int w   = tid >> 6;   // 0..7
    const int wm  = w >> 2;     // 0..1 -> rows wm*64
    const int wn  = w & 3;      // 0..3 -> cols wn*32
    const int bx  = blockIdx.x;
    const int mt  = bx & 127;
    const int nh  = bx >> 7;

    const char* Aimg = ws_c + AIMG_OFF;
    const char* Bimg = ws_c;

    if (tid < 256) {
        float o0 = ola[tid], o1 = ola[tid + 256], o2 = ola[tid + 512], o3 = ola[tid + 768];
        s_wsum[tid] = o0 + o1 + o2 + o3;
        s_ola0[tid] = o0;
        s_ola3[tid] = o3;
    }

    const bool lo_edge = ((mt & 15) == 0);
    const bool hi_edge = ((mt & 15) == 15);

    f32x4 acc[4][2];
#pragma unroll
    for (int i = 0; i < 4; ++i)
#pragma unroll
        for (int n = 0; n < 2; ++n) acc[i][n] = (f32x4){0.f, 0.f, 0.f, 0.f};

    auto STAGE = [&](int kt, int buf) {
        int j2  = kt / 17;
        int c0b = (kt - j2 * 17) << 7;     // (kt%17)*128 bytes
        const char* asrc = Aimg + (ptrdiff_t)(mt * 128 + 2 - j2) * APITCH + c0b
                         + (ptrdiff_t)(tid >> 3) * APITCH + (tid & 7) * 16;
        char* adst = (char*)&Abuf[buf][0][0] + w * 1024;
        const char* bsrc = Bimg + (size_t)(kt * 2 + nh) * 16384 + tid * 16;
        char* bdst = (char*)&Bbuf[buf][0][0] + w * 1024;
        __builtin_amdgcn_global_load_lds((const __attribute__((address_space(1))) unsigned*)asrc,
                                         (__attribute__((address_space(3))) unsigned*)adst, 16, 0, 0);
        __builtin_amdgcn_global_load_lds((const __attribute__((address_space(1))) unsigned*)(asrc + (ptrdiff_t)64 * APITCH),
                                         (__attribute__((address_space(3))) unsigned*)(adst + 8192), 16, 0, 0);
        __builtin_amdgcn_global_load_lds((const __attribute__((address_space(1))) unsigned*)bsrc,
                                         (__attribute__((address_space(3))) unsigned*)bdst, 16, 0, 0);
        __builtin_amdgcn_global_load_lds((const __attribute__((address_space(1))) unsigned*)(bsrc + 8192),
                                         (__attribute__((address_space(3))) unsigned*)(bdst + 8192), 16, 0, 0);
    };

    auto ZFIX = [&](int buf, int j) {
        // zero LDS rows whose source frame t = gi+2-j is out of [0,2048)
        if (lo_edge && j == 3) {
            if (tid < 8) *(f32x4*)((char*)&Abuf[buf][0][0] + tid * 16) = (f32x4){0.f,0.f,0.f,0.f};
            asm volatile("s_waitcnt lgkmcnt(0)" ::: "memory");
            __builtin_amdgcn_s_barrier();
            __builtin_amdgcn_sched_barrier(0);
        } else if (hi_edge && j <= 1) {
            if (j == 0) {
                if (tid < 16) *(f32x4*)((char*)&Abuf[buf][0][0] + 126 * 128 + tid * 16) = (f32x4){0.f,0.f,0.f,0.f};
            } else {
                if (tid < 8)  *(f32x4*)((char*)&Abuf[buf][0][0] + 127 * 128 + tid * 16) = (f32x4){0.f,0.f,0.f,0.f};
            }
            asm volatile("s_waitcnt lgkmcnt(0)" ::: "memory");
            __builtin_amdgcn_s_barrier();
            __builtin_amdgcn_sched_barrier(0);
        }
    };

    auto COMPUTE = [&](int buf, int rp) {
        const char* Ab = (const char*)&Abuf[buf][0][0];
        const char* Bb = (const char*)&Bbuf[buf][0][0];
#pragma unroll
        for (int ks = 0; ks < 2; ++ks) {
            const int grpK = ks * 4 + (l >> 4);
            bf16x8 af[4], bfr[2];
#pragma unroll
            for (int mb = 0; mb < 4; ++mb) {
                int row = wm * 64 + mb * 16 + (l & 15);
                af[mb] = *(const bf16x8*)(Ab + row * 128 + ((grpK ^ ((row + rp) & 7)) << 4));
            }
#pragma unroll
            for (int nb = 0; nb < 2; ++nb) {
                int nn = wn * 32 + nb * 16 + (l & 15);
                bfr[nb] = *(const bf16x8*)(Bb + nn * 128 + ((grpK ^ (nn & 7)) << 4));
            }
            __builtin_amdgcn_s_setprio(1);
#pragma unroll
            for (int mb = 0; mb < 4; ++mb)
#pragma unroll
                for (int nb = 0; nb < 2; ++nb)
                    acc[mb][nb] = __builtin_amdgcn_mfma_f32_16x16x32_bf16(af[mb], bfr[nb], acc[mb][nb], 0, 0, 0);
            __builtin_amdgcn_s_setprio(0);
        }
    };

    // ---- pipeline ----
    STAGE(0, 0);
    STAGE(1, 1);
    asm volatile("s_waitcnt vmcnt(4)" ::: "memory");
    __builtin_amdgcn_s_barrier();
    __builtin_amdgcn_sched_barrier(0);

    int j = 0, ktm = 0;
    for (int i = 0; i < NKT; ++i) {
        if (i + 2 < NKT) {
            STAGE(i + 2, (i + 2) % 3);
            asm volatile("s_waitcnt vmcnt(8)" ::: "memory");
        } else if (i + 1 < NKT) {
            asm volatile("s_waitcnt vmcnt(4)" ::: "memory");
        } else {
            asm volatile("s_waitcnt vmcnt(0)" ::: "memory");
        }
        __builtin_amdgcn_s_barrier();
        __builtin_amdgcn_sched_barrier(0);
        ZFIX(i % 3, j);
        COMPUTE(i % 3, (10 - j) & 7);   // rp = (2-j) mod 8
        __builtin_amdgcn_s_barrier();
        __builtin_amdgcn_sched_barrier(0);
        if (++ktm == 17) { ktm = 0; ++j; }
    }

    // ---- epilogue ----
#pragma unroll
    for (int mb = 0; mb < 4; ++mb) {
#pragma unroll
        for (int rr = 0; rr < 4; ++rr) {
            int ml = wm * 64 + mb * 16 + (l >> 4) * 4 + rr;
            int mg = mt * 128 + ml;
            int bb = mg >> 11;
            int gi = mg & 2047;
            if (gi > 2046) continue;
#pragma unroll
            for (int nb = 0; nb < 2; ++nb) {
                int n = nh * 128 + wn * 32 + nb * 16 + (l & 15);
                float wsv = s_wsum[n];
                if (gi == 0)    wsv -= s_ola3[n];
                if (gi == 2046) wsv -= s_ola0[n];
                wsv = fmaxf(wsv, 1e-11f);
                out[(size_t)(bb * 2047 + gi) * 256 + n] = acc[mb][nb][rr] / wsv;
            }
        }
    }
}

// ===================== v3 fallback (round-3, passed @116us) =====================
__global__ __launch_bounds__(256) void prep_B3(const float* __restrict__ Wr,
                                               const float* __restrict__ Wi,
                                               unsigned short* __restrict__ Bs) {
    int id  = blockIdx.x * 256 + threadIdx.x;
    int kt  = id >> 13;
    int rem = id & 8191;
    int n   = rem >> 5;
    int k0  = (rem & 31) * 2;
    unsigned short h[2];
#pragma unroll
    for (int i = 0; i < 2; ++i) {
        int k  = k0 + i;
        int kg = kt * 64 + k;
        int kk = kg >> 2;
        int j  = kg & 3;
        float v = 0.0f;
        if (kk < FREQ) {
            float f = (kk == 0 || kk == FREQ - 1) ? 1.0f : 2.0f;
            v = f * Wr[(size_t)kk * NFFT + n + 256 * j];
        } else if (kk < 2 * FREQ) {
            int k2 = kk - FREQ;
            float f = (k2 == 0 || k2 == FREQ - 1) ? 1.0f : 2.0f;
            v = -f * Wi[(size_t)k2 * NFFT + n + 256 * j];
        }
        h[i] = f2bf(v);
    }
    unsigned d = (unsigned)h[0] | ((unsigned)h[1] << 16);
    unsigned byteoff = (unsigned)((n << 7) + (k0 << 1)) ^ (unsigned)((n & 7) << 4);
    *(unsigned*)((char*)Bs + (size_t)kt * 32768 + byteoff) = d;
}

__global__ __launch_bounds__(512, 2) void istft_mfma3(
    const float* __restrict__ re, const float* __restrict__ im,
    const float* __restrict__ ola, const unsigned short* __restrict__ Bs,
    float* __restrict__ out) {
    __shared__ __attribute__((aligned(16))) unsigned short Abuf[2][64][72];
    __shared__ __attribute__((aligned(16))) unsigned short Bbuf[2][16384];
    __shared__ float s_wsum[256], s_ola0[256], s_ola3[256];
    const int tid = threadIdx.x;
    const int l = tid & 63, w = tid >> 6, wm = w >> 2, wn = w & 3, mt = blockIdx.x;
    if (tid < 256) {
        float o0 = ola[tid], o1 = ola[tid + 256], o2 = ola[tid + 512], o3 = ola[tid + 768];
        s_wsum[tid] = o0 + o1 + o2 + o3; s_ola0[tid] = o0; s_ola3[tid] = o3;
    }
    const int r = tid >> 3, o = tid & 7;
    const int m = mt * 64 + r;
    int b = 0, gi = 0;
    const bool mrow_ok = (m < 16376);
    if (mrow_ok) { b = m / 2047; gi = m - b * 2047; }
    const int g = gi + 2;
    int baseT[4];
#pragma unroll
    for (int jj = 0; jj < 4; ++jj) {
        int t = g - jj;
        baseT[jj] = (mrow_ok && t >= 0 && t < NFRAMES) ? (b * NFRAMES + t) * FREQ : -1;
    }
    float areg[8];
    auto A_LOAD = [&](int kt) {
        int kkbase = kt * 16 + o * 2;
#pragma unroll
        for (int d = 0; d < 2; ++d) {
            int kk = kkbase + d;
#pragma unroll
            for (int jj = 0; jj < 4; ++jj) {
                float v = 0.0f;
                if (baseT[jj] >= 0) {
                    if (kk < FREQ) v = re[baseT[jj] + kk];
                    else if (kk < 2 * FREQ) v = im[baseT[jj] + kk - FREQ];
                }
                areg[d * 4 + jj] = v;
            }
        }
    };
    auto A_WRITE = [&](int buf) {
        bf16x8 v;
#pragma unroll
        for (int i = 0; i < 8; ++i) v[i] = (short)f2bf(areg[i]);
        *(bf16x8*)&Abuf[buf][r][o * 8] = v;
    };
    auto B_STAGE = [&](int kt, int buf) {
        const char* src = (const char*)Bs + (size_t)kt * 32768 + (size_t)w * 4096 + (size_t)l * 16;
        char* dst = (char*)&Bbuf[buf][0] + w * 4096;
#pragma unroll
        for (int c = 0; c < 4; ++c)
            __builtin_amdgcn_global_load_lds(
                (const __attribute__((address_space(1))) unsigned*)(src + c * 1024),
                (__attribute__((address_space(3))) unsigned*)(dst + c * 1024), 16, 0, 0);
    };
    f32x4 acc[2][4];
#pragma unroll
    for (int i = 0; i < 2; ++i)
#pragma unroll
        for (int n = 0; n < 4; ++n) acc[i][n] = (f32x4){0.f, 0.f, 0.f, 0.f};
    auto COMPUTE = [&](int buf) {
#pragma unroll
        for (int ks = 0; ks < 2; ++ks) {
            const int krow = ks * 32 + (l >> 4) * 8;
            bf16x8 af[2], bfr[4];
#pragma unroll
            for (int mb = 0; mb < 2; ++mb)
                af[mb] = *(const bf16x8*)&Abuf[buf][wm * 32 + mb * 16 + (l & 15)][krow];
#pragma unroll
            for (int nb = 0; nb < 4; ++nb) {
                const int nn = wn * 64 + nb * 16 + (l & 15);
                unsigned off = (unsigned)((nn << 7) + (krow << 1)) ^ (unsigned)((nn & 7) << 4);
                bfr[nb] = *(const bf16x8*)((const char*)&Bbuf[buf][0] + off);
            }
#pragma unroll
            for (int mb = 0; mb < 2; ++mb)
#pragma unroll
                for (int nb = 0; nb < 4; ++nb)
                    acc[mb][nb] = __builtin_amdgcn_mfma_f32_16x16x32_bf16(af[mb], bfr[nb], acc[mb][nb], 0, 0, 0);
        }
    };
    A_LOAD(0); B_STAGE(0, 0); A_WRITE(0);
    __syncthreads();
    for (int kt = 0; kt < 66; ++kt) {
        const int cur = kt & 1, nxt = cur ^ 1;
        if (kt + 1 < 66) { A_LOAD(kt + 1); B_STAGE(kt + 1, nxt); }
        COMPUTE(cur);
        if (kt + 1 < 66) A_WRITE(nxt);
        __syncthreads();
    }
#pragma unroll
    for (int mb = 0; mb < 2; ++mb) {
#pragma unroll
        for (int rr = 0; rr < 4; ++rr) {
            int ml = wm * 32 + mb * 16 + (l >> 4) * 4 + rr;
            int mg = mt * 64 + ml;
            if (mg >= 16376) continue;
            int bb = mg / 2047;
            int gg = mg - bb * 2047;
#pragma unroll
            for (int nb = 0; nb < 4; ++nb) {
                int n = wn * 64 + nb * 16 + (l & 15);
                float wsv = s_wsum[n];
                if (gg == 0)    wsv -= s_ola3[n];
                if (gg == 2046) wsv -= s_ola0[n];
                wsv = fmaxf(wsv, 1e-11f);
                out[(size_t)mg * 256 + n] = acc[mb][nb][rr] / wsv;
            }
        }
    }
}

// ---------------- last-resort naive (round-1) ----------------
__global__ __launch_bounds__(256) void istft_naive(
    const float* __restrict__ re, const float* __restrict__ im,
    const float* __restrict__ Wr, const float* __restrict__ Wi,
    const float* __restrict__ ola, float* __restrict__ out) {
    const int g = blockIdx.x + 2, b = blockIdx.y, ls = threadIdx.x;
    __shared__ float s_fr[4][FREQ];
    __shared__ float s_fi[4][FREQ];
#pragma unroll
    for (int jj = 0; jj < 4; ++jj) {
        const int t = g - jj;
        const bool valid = (t >= 0 && t < NFRAMES);
        const size_t base = ((size_t)b * NFRAMES + (valid ? t : 0)) * FREQ;
        for (int k = ls; k < FREQ; k += 256) {
            const float f = (k == 0 || k == FREQ - 1) ? 1.0f : 2.0f;
            s_fr[jj][k] = valid ? re[base + k] * f : 0.0f;
            s_fi[jj][k] = valid ? im[base + k] * f : 0.0f;
        }
    }
    __syncthreads();
    const float* wr = Wr + ls;
    const float* wi = Wi + ls;
    float acc = 0.0f;
    for (int k = 0; k < FREQ; ++k) {
        const float* wrk = wr + (size_t)k * NFFT;
        const float* wik = wi + (size_t)k * NFFT;
#pragma unroll
        for (int jj = 0; jj < 4; ++jj) {
            acc = fmaf(wrk[jj * 256], s_fr[jj][k], acc);
            acc = fmaf(-wik[jj * 256], s_fi[jj][k], acc);
        }
    }
    float wsv = 0.0f;
#pragma unroll
    for (int jj = 0; jj < 4; ++jj) {
        const int t = g - jj;
        if (t >= 0 && t < NFRAMES) wsv += ola[ls + jj * 256];
    }
    wsv = fmaxf(wsv, 1e-11f);
    out[(size_t)b * OUTCOLS + (g * 256 + ls - 512)] = acc / wsv;
}

extern "C" void kernel_launch(void* const* d_in, const int* in_sizes, int n_in,
                              void* d_out, int out_size, void* d_ws, size_t ws_size,
                              hipStream_t stream) {
    const float* re  = (const float*)d_in[0];
    const float* im  = (const float*)d_in[1];
    const float* Wr  = (const float*)d_in[2];
    const float* Wi  = (const float*)d_in[3];
    const float* ola = (const float*)d_in[4];
    float* out = (float*)d_out;

    if (ws_size >= WS_NEED) {
        char* ws = (char*)d_ws;
        hipLaunchKernelGGL(prep_B4, dim3(2176), dim3(256), 0, stream, Wr, Wi, ws);
        hipLaunchKernelGGL(prep_A, dim3(16384), dim3(256), 0, stream, re, im, ws);
        hipLaunchKernelGGL(istft_mfma4, dim3(256), dim3(512), 0, stream, ws, ola, out);
    } else if (ws_size >= (size_t)BSBYTES_V3) {
        unsigned short* Bs = (unsigned short*)d_ws;
        hipLaunchKernelGGL(prep_B3, dim3(2112), dim3(256), 0, stream, Wr, Wi, Bs);
        hipLaunchKernelGGL(istft_mfma3, dim3(256), dim3(512), 0, stream, re, im, ola, Bs, out);
    } else {
        dim3 grid(2047, BATCH);
        hipLaunchKernelGGL(istft_naive, grid, dim3(256), 0, stream, re, im, Wr, Wi, ola, out);
    }
}

// Round 5
// 101.690 us; speedup vs baseline: 21.1288x; 1.0745x over previous
//
#include <hip/hip_runtime.h>

// Fused ISTFT as one MFMA GEMM, j-major K layout:
//   out[(b,g)][n] = ( sum_{k''} A[m'][k''] * Bfold[k''][n] ) / wsum[n]
// k'' = j*1088 + c; c<544: re[kk=c], else im[kk=c-544] (valid kk<513, zero-pad).
// A image rows = frame rows f = b*2048 + t (bf16, row-phase-XOR-swizzled).
// Bfold[j*1088+c][n] = f(kk)*Wr[kk][n+256j] / -f(kk)*Wi[kk][n+256j], f=2 except DC/Nyq.
// out flat = (b*2047+gi)*256 + n.
//
// Round 5: BM=64 x BN=128, 256-thread blocks, depth-3, 75KB LDS -> 2 independent
// blocks/CU (break barrier lockstep); merged full-utilization prep kernel.

#define BATCH    8
#define NFRAMES  2048
#define FREQ     513
#define NFFT     1024
#define OUTCOLS  524032
#define NKT      68            // K'' = 4352 = 68*64
#define APITCH   2176          // bytes per frame row (1088 bf16)
#define BSB      (NKT * 32768) // 2,228,224 B (68 tiles x 2 halves x 16KB)
#define GUARDB   (64 * APITCH)
#define AIMG_OFF ((size_t)BSB + GUARDB)
#define WS_NEED  (AIMG_OFF + (size_t)16384 * APITCH + GUARDB)

#define PA_BLOCKS 8704         // 8704*256 = 16384*136 thread-groups
#define PB_BLOCKS 2176         // 2176*256 = 136*4096 dwords

typedef __attribute__((ext_vector_type(8))) short bf16x8;
typedef __attribute__((ext_vector_type(4))) float f32x4;

__device__ __forceinline__ unsigned short f2bf(float x) {
    unsigned u = __float_as_uint(x);
    return (unsigned short)((u + 0x7fffu + ((u >> 16) & 1u)) >> 16);
}

// ============ merged prep: A-image repack + B build, full utilization ============
__global__ __launch_bounds__(256) void prep_AB(const float* __restrict__ re,
                                               const float* __restrict__ im,
                                               const float* __restrict__ Wr,
                                               const float* __restrict__ Wi,
                                               char* __restrict__ ws) {
    const int bx = blockIdx.x;
    if (bx < PA_BLOCKS) {
        // ---- A: row-phase-swizzled bf16 image ----
        unsigned gid = (unsigned)bx * 256u + threadIdx.x;
        unsigned row = gid / 136u;
        int g8 = (int)(gid - row * 136u);
        const float* src = (g8 < 68) ? (re + (size_t)row * FREQ) : (im + (size_t)row * FREQ);
        const int cbase = (g8 < 68) ? g8 * 8 : g8 * 8 - 544;
        bf16x8 v;
#pragma unroll
        for (int e = 0; e < 8; ++e) {
            int c = cbase + e;
            float x = (c < FREQ) ? src[c] : 0.0f;
            v[e] = (short)f2bf(x);
        }
        char* dst = ws + AIMG_OFF + (size_t)row * APITCH
                  + (g8 >> 3) * 128 + (((g8 & 7) ^ ((int)row & 7)) << 4);
        *(bf16x8*)dst = v;
    } else {
        // ---- B: 68 tiles x 2 halves x [128 nn][64 k], XOR-pre-swizzled ----
        int id = (bx - PA_BLOCKS) * 256 + threadIdx.x;
        int hid  = id >> 12;        // kt*2+nh (0..135)
        int rem  = id & 4095;
        int nn   = rem >> 5;        // 0..127
        int dstd = rem & 31;        // stored dword-in-row
        int dsrc = dstd ^ ((nn & 7) << 2);
        int kt = hid >> 1, nh = hid & 1;
        int kg = kt * 64 + dsrc * 2;
        int j  = kg / 1088;
        int c  = kg - j * 1088;
        int col = nh * 128 + nn + 256 * j;
        unsigned short h[2];
#pragma unroll
        for (int e = 0; e < 2; ++e) {
            int ce = c + e;
            float v = 0.0f;
            if (ce < 544) {
                if (ce < FREQ) {
                    float f = (ce == 0 || ce == FREQ - 1) ? 1.0f : 2.0f;
                    v = f * Wr[(size_t)ce * NFFT + col];
                }
            } else {
                int ci = ce - 544;
                if (ci < FREQ) {
                    float f = (ci == 0 || ci == FREQ - 1) ? 1.0f : 2.0f;
                    v = -f * Wi[(size_t)ci * NFFT + col];
                }
            }
            h[e] = f2bf(v);
        }
        unsigned d = (unsigned)h[0] | ((unsigned)h[1] << 16);
        *(unsigned*)(ws + (size_t)hid * 16384 + nn * 128 + dstd * 4) = d;
    }
}

// ============ main kernel: BM=64 x BN=128, 4 waves, depth-3, 2 blocks/CU ============
__global__ __launch_bounds__(256, 2) void istft_mfma5(
    const char* __restrict__ ws_c, const float* __restrict__ ola,
    float* __restrict__ out) {
    __shared__ __attribute__((aligned(16))) unsigned short Abuf[3][64][64];  // 24KB
    __shared__ __attribute__((aligned(16))) unsigned short Bbuf[3][128][64]; // 48KB
    __shared__ float s_wsum[256], s_ola0[256], s_ola3[256];

    const int tid = threadIdx.x;
    const int l   = tid & 63;
    const int w   = tid >> 6;   // 0..3 = N quarter

    // XCD-bijective swizzle (512 = 8*64): nh pairs adjacent on same XCD
    const int bx  = blockIdx.x;
    const int sid = (bx & 7) * 64 + (bx >> 3);
    const int mt  = sid >> 1;   // 0..255
    const int nh  = sid & 1;

    const char* Aimg = ws_c + AIMG_OFF;
    const char* Bimg = ws_c;

    {
        float o0 = ola[tid], o1 = ola[tid + 256], o2 = ola[tid + 512], o3 = ola[tid + 768];
        s_wsum[tid] = o0 + o1 + o2 + o3;
        s_ola0[tid] = o0;
        s_ola3[tid] = o3;
    }

    const bool lo_edge = ((mt & 31) == 0);
    const bool hi_edge = ((mt & 31) == 31);

    f32x4 acc[4][2];
#pragma unroll
    for (int i = 0; i < 4; ++i)
#pragma unroll
        for (int n = 0; n < 2; ++n) acc[i][n] = (f32x4){0.f, 0.f, 0.f, 0.f};

    auto STAGE = [&](int kt, int buf) {
        int j2  = kt / 17;
        int c0b = (kt - j2 * 17) << 7;
        const char* asrc = Aimg + (ptrdiff_t)(mt * 64 + 2 - j2) * APITCH + c0b
                         + (ptrdiff_t)(tid >> 3) * APITCH + (tid & 7) * 16;
        char* adst = (char*)&Abuf[buf][0][0] + w * 1024;
        const char* bsrc = Bimg + (size_t)(kt * 2 + nh) * 16384 + (size_t)tid * 16;
        char* bdst = (char*)&Bbuf[buf][0][0] + w * 1024;
        __builtin_amdgcn_global_load_lds((const __attribute__((address_space(1))) unsigned*)asrc,
                                         (__attribute__((address_space(3))) unsigned*)adst, 16, 0, 0);
        __builtin_amdgcn_global_load_lds((const __attribute__((address_space(1))) unsigned*)(asrc + (ptrdiff_t)32 * APITCH),
                                         (__attribute__((address_space(3))) unsigned*)(adst + 4096), 16, 0, 0);
#pragma unroll
        for (int c = 0; c < 4; ++c)
            __builtin_amdgcn_global_load_lds((const __attribute__((address_space(1))) unsigned*)(bsrc + c * 4096),
                                             (__attribute__((address_space(3))) unsigned*)(bdst + c * 4096), 16, 0, 0);
    };

    auto ZFIX = [&](int buf, int j) {
        // zero LDS A-rows whose source frame t = gi+2-j is out of [0,2048)
        if (lo_edge && j == 3) {
            if (tid < 8) *(f32x4*)((char*)&Abuf[buf][0][0] + tid * 16) = (f32x4){0.f,0.f,0.f,0.f};
            asm volatile("s_waitcnt lgkmcnt(0)" ::: "memory");
            __builtin_amdgcn_s_barrier();
            __builtin_amdgcn_sched_barrier(0);
        } else if (hi_edge && j <= 1) {
            if (j == 0) {
                if (tid < 16) *(f32x4*)((char*)&Abuf[buf][0][0] + 62 * 128 + tid * 16) = (f32x4){0.f,0.f,0.f,0.f};
            } else {
                if (tid < 8)  *(f32x4*)((char*)&Abuf[buf][0][0] + 63 * 128 + tid * 16) = (f32x4){0.f,0.f,0.f,0.f};
            }
            asm volatile("s_waitcnt lgkmcnt(0)" ::: "memory");
            __builtin_amdgcn_s_barrier();
            __builtin_amdgcn_sched_barrier(0);
        }
    };

    auto COMPUTE = [&](int buf, int rp) {
        const char* Ab = (const char*)&Abuf[buf][0][0];
        const char* Bb = (const char*)&Bbuf[buf][0][0];
#pragma unroll
        for (int ks = 0; ks < 2; ++ks) {
            const int grpK = ks * 4 + (l >> 4);
            bf16x8 af[4], bfr[2];
#pragma unroll
            for (int mb = 0; mb < 4; ++mb) {
                int row = mb * 16 + (l & 15);
                af[mb] = *(const bf16x8*)(Ab + row * 128 + ((grpK ^ ((row + rp) & 7)) << 4));
            }
#pragma unroll
            for (int nb = 0; nb < 2; ++nb) {
                int nn = w * 32 + nb * 16 + (l & 15);
                bfr[nb] = *(const bf16x8*)(Bb + nn * 128 + ((grpK ^ (nn & 7)) << 4));
            }
            __builtin_amdgcn_s_setprio(1);
#pragma unroll
            for (int mb = 0; mb < 4; ++mb)
#pragma unroll
                for (int nb = 0; nb < 2; ++nb)
                    acc[mb][nb] = __builtin_amdgcn_mfma_f32_16x16x32_bf16(af[mb], bfr[nb], acc[mb][nb], 0, 0, 0);
            __builtin_amdgcn_s_setprio(0);
        }
    };

    // ---- pipeline: depth 3, counted vmcnt (6 loads per STAGE) ----
    STAGE(0, 0);
    STAGE(1, 1);
    asm volatile("s_waitcnt vmcnt(6)" ::: "memory");
    __builtin_amdgcn_s_barrier();
    __builtin_amdgcn_sched_barrier(0);

    int j = 0, ktm = 0;
    for (int i = 0; i < NKT; ++i) {
        if (i + 2 < NKT) {
            STAGE(i + 2, (i + 2) % 3);
            asm volatile("s_waitcnt vmcnt(12)" ::: "memory");
        } else if (i + 1 < NKT) {
            asm volatile("s_waitcnt vmcnt(6)" ::: "memory");
        } else {
            asm volatile("s_waitcnt vmcnt(0)" ::: "memory");
        }
        __builtin_amdgcn_s_barrier();
        __builtin_amdgcn_sched_barrier(0);
        ZFIX(i % 3, j);
        COMPUTE(i % 3, (10 - j) & 7);   // rp = (2-j) mod 8
        __builtin_amdgcn_s_barrier();
        __builtin_amdgcn_sched_barrier(0);
        if (++ktm == 17) { ktm = 0; ++j; }
    }

    // ---- epilogue ----
#pragma unroll
    for (int mb = 0; mb < 4; ++mb) {
#pragma unroll
        for (int rr = 0; rr < 4; ++rr) {
            int ml = mb * 16 + (l >> 4) * 4 + rr;
            int mg = mt * 64 + ml;
            int bb = mg >> 11;
            int gi = mg & 2047;
            if (gi > 2046) continue;
#pragma unroll
            for (int nb = 0; nb < 2; ++nb) {
                int n = nh * 128 + w * 32 + nb * 16 + (l & 15);
                float wsv = s_wsum[n];
                if (gi == 0)    wsv -= s_ola3[n];
                if (gi == 2046) wsv -= s_ola0[n];
                wsv = fmaxf(wsv, 1e-11f);
                out[(size_t)(bb * 2047 + gi) * 256 + n] = acc[mb][nb][rr] / wsv;
            }
        }
    }
}

// ---------------- last-resort naive fallback ----------------
__global__ __launch_bounds__(256) void istft_naive(
    const float* __restrict__ re, const float* __restrict__ im,
    const float* __restrict__ Wr, const float* __restrict__ Wi,
    const float* __restrict__ ola, float* __restrict__ out) {
    const int g = blockIdx.x + 2, b = blockIdx.y, ls = threadIdx.x;
    __shared__ float s_fr[4][FREQ];
    __shared__ float s_fi[4][FREQ];
#pragma unroll
    for (int jj = 0; jj < 4; ++jj) {
        const int t = g - jj;
        const bool valid = (t >= 0 && t < NFRAMES);
        const size_t base = ((size_t)b * NFRAMES + (valid ? t : 0)) * FREQ;
        for (int k = ls; k < FREQ; k += 256) {
            const float f = (k == 0 || k == FREQ - 1) ? 1.0f : 2.0f;
            s_fr[jj][k] = valid ? re[base + k] * f : 0.0f;
            s_fi[jj][k] = valid ? im[base + k] * f : 0.0f;
        }
    }
    __syncthreads();
    const float* wr = Wr + ls;
    const float* wi = Wi + ls;
    float acc = 0.0f;
    for (int k = 0; k < FREQ; ++k) {
        const float* wrk = wr + (size_t)k * NFFT;
        const float* wik = wi + (size_t)k * NFFT;
#pragma unroll
        for (int jj = 0; jj < 4; ++jj) {
            acc = fmaf(wrk[jj * 256], s_fr[jj][k], acc);
            acc = fmaf(-wik[jj * 256], s_fi[jj][k], acc);
        }
    }
    float wsv = 0.0f;
#pragma unroll
    for (int jj = 0; jj < 4; ++jj) {
        const int t = g - jj;
        if (t >= 0 && t < NFRAMES) wsv += ola[ls + jj * 256];
    }
    wsv = fmaxf(wsv, 1e-11f);
    out[(size_t)b * OUTCOLS + (g * 256 + ls - 512)] = acc / wsv;
}

extern "C" void kernel_launch(void* const* d_in, const int* in_sizes, int n_in,
                              void* d_out, int out_size, void* d_ws, size_t ws_size,
                              hipStream_t stream) {
    const float* re  = (const float*)d_in[0];
    const float* im  = (const float*)d_in[1];
    const float* Wr  = (const float*)d_in[2];
    const float* Wi  = (const float*)d_in[3];
    const float* ola = (const float*)d_in[4];
    float* out = (float*)d_out;

    if (ws_size >= WS_NEED) {
        char* ws = (char*)d_ws;
        hipLaunchKernelGGL(prep_AB, dim3(PA_BLOCKS + PB_BLOCKS), dim3(256), 0, stream,
                           re, im, Wr, Wi, ws);
        hipLaunchKernelGGL(istft_mfma5, dim3(512), dim3(256), 0, stream, ws, ola, out);
    } else {
        dim3 grid(2047, BATCH);
        hipLaunchKernelGGL(istft_naive, grid, dim3(256), 0, stream, re, im, Wr, Wi, ola, out);
    }
}